// Round 1
// baseline (402.271 us; speedup 1.0000x reference)
//
#include <hip/hip_runtime.h>
#include <hip/hip_bf16.h>
#include <math.h>

// Shapes (fixed by the reference)
#define B_GRAPHS 512
#define MAXLEN   128
#define DDRUG    256
#define DCELL    1024
#define NH       16
#define HDIM     64
#define EMB      1024

// ---------------------------------------------------------------------------
// starts[b] = lower_bound(guide, b), b in [0,512]; guide is sorted.
// Handles guide stored as int32 OR int64: index N-1 is odd, so for little-
// endian int64 storage g32[N-1] is a high word (== 0 since ids < 512); for
// int32 storage it is the max graph id (> 0).
// ---------------------------------------------------------------------------
__global__ void starts_kernel(const int* __restrict__ g32, int N, int* __restrict__ starts)
{
    int b = blockIdx.x * blockDim.x + threadIdx.x;
    if (b > B_GRAPHS) return;
    bool is64 = (g32[N - 1] == 0);
    int lo = 0, hi = N;
    while (lo < hi) {
        int mid = (lo + hi) >> 1;
        int v = is64 ? g32[2 * mid] : g32[mid];
        if (v < b) lo = mid + 1; else hi = mid;
    }
    starts[b] = lo;
}

// ---------------------------------------------------------------------------
// C[M,N] = (A[M,K] * B[N,K]^T + bias[N]) * scale     (both operands k-major)
// BM=32, BN=64, BK=16, 256 threads, 2x4 micro-tile. Grid covers M,N exactly.
// ---------------------------------------------------------------------------
#define BM 32
#define BN 64
#define BK 16

__global__ __launch_bounds__(256) void gemm_nt(
    const float* __restrict__ A, const float* __restrict__ Bw,
    const float* __restrict__ bias, float* __restrict__ C,
    int K, int lda, int ldb, int ldc, float scale)
{
    __shared__ alignas(16) float As[BK][BM + 4];   // pitch 36 floats (144B, 8B-aligned reads)
    __shared__ alignas(16) float Bs[BK][BN + 4];   // pitch 68 floats (272B, 16B-aligned reads)
    const int t  = threadIdx.x;
    const int tx = t & 15, ty = t >> 4;
    const int row0 = blockIdx.y * BM, col0 = blockIdx.x * BN;
    float acc[2][4] = {};

    for (int kt = 0; kt < K; kt += BK) {
        #pragma unroll
        for (int i = 0; i < (BM * BK) / 256; ++i) {
            int idx = t + i * 256;                 // k fastest -> coalesced 64B rows
            As[idx & 15][idx >> 4] = A[(size_t)(row0 + (idx >> 4)) * lda + kt + (idx & 15)];
        }
        #pragma unroll
        for (int i = 0; i < (BN * BK) / 256; ++i) {
            int idx = t + i * 256;
            Bs[idx & 15][idx >> 4] = Bw[(size_t)(col0 + (idx >> 4)) * ldb + kt + (idx & 15)];
        }
        __syncthreads();
        #pragma unroll
        for (int k = 0; k < BK; ++k) {
            float2 a2 = *(const float2*)&As[k][ty * 2];
            float4 b4 = *(const float4*)&Bs[k][tx * 4];
            acc[0][0] += a2.x * b4.x; acc[0][1] += a2.x * b4.y;
            acc[0][2] += a2.x * b4.z; acc[0][3] += a2.x * b4.w;
            acc[1][0] += a2.y * b4.x; acc[1][1] += a2.y * b4.y;
            acc[1][2] += a2.y * b4.z; acc[1][3] += a2.y * b4.w;
        }
        __syncthreads();
    }
    #pragma unroll
    for (int j = 0; j < 2; ++j) {
        int r = row0 + ty * 2 + j;
        #pragma unroll
        for (int i = 0; i < 4; ++i) {
            int c = col0 + tx * 4 + i;
            C[(size_t)r * ldc + c] = (acc[j][i] + bias[c]) * scale;
        }
    }
}

// ---------------------------------------------------------------------------
// qk[b, h, d] = sum_j q[b, h*64+j] * Wk[h*64+j, d]
// block = (b-tile of 8, h); 256 threads = d. Wk slice stays hot in L2.
// ---------------------------------------------------------------------------
__global__ __launch_bounds__(256) void qk_kernel(
    const float* __restrict__ q, const float* __restrict__ Wk, float* __restrict__ qkout)
{
    __shared__ float q_s[8][64];
    const int bt = blockIdx.x, h = blockIdx.y, t = threadIdx.x;
    for (int i = t; i < 512; i += 256)
        q_s[i >> 6][i & 63] = q[(size_t)(bt * 8 + (i >> 6)) * EMB + h * 64 + (i & 63)];
    __syncthreads();
    float acc[8] = {};
    const float* wbase = &Wk[(size_t)h * 64 * DDRUG + t];
    #pragma unroll 4
    for (int j = 0; j < 64; ++j) {
        float wv = wbase[(size_t)j * DDRUG];       // coalesced across threads
        #pragma unroll
        for (int bb = 0; bb < 8; ++bb) acc[bb] += q_s[bb][j] * wv;
    }
    #pragma unroll
    for (int bb = 0; bb < 8; ++bb)
        qkout[(size_t)(bt * 8 + bb) * (NH * DDRUG) + h * DDRUG + t] = acc[bb];
}

// ---------------------------------------------------------------------------
// Per-graph: scores = X_b . qk_b^T, masked softmax over valid rows,
// xbar[b,h,:] = sum_m attn[m,h] * X_b[m,:].   block = graph b, 256 thr.
// bk is softmax-invariant (dropped); sum(attn)=1 handles bv downstream.
// ---------------------------------------------------------------------------
__global__ __launch_bounds__(256) void attn_kernel(
    const float* __restrict__ X, const float* __restrict__ qk,
    const int* __restrict__ starts, float* __restrict__ xbar)
{
    __shared__ alignas(16) float qk_s[NH * DDRUG];  // 16 KB
    __shared__ float s_s[MAXLEN * 17];              // pitch 17 -> no bank conflicts
    const int b = blockIdx.x, t = threadIdx.x;
    const int lane = t & 63, w = t >> 6;
    const int s0 = starts[b];
    int n = starts[b + 1] - s0;
    if (n > MAXLEN) n = MAXLEN;                     // to_dense_batch drops pos >= 128

    for (int i = t; i < (NH * DDRUG) / 4; i += 256)
        *(float4*)&qk_s[i * 4] = *(const float4*)&qk[(size_t)b * (NH * DDRUG) + i * 4];
    __syncthreads();

    // scores: wave w handles rows m = w, w+4, ...
    for (int m = w; m < n; m += 4) {
        float4 x4 = *(const float4*)&X[(size_t)(s0 + m) * DDRUG + lane * 4];
        #pragma unroll
        for (int h = 0; h < NH; ++h) {
            float4 q4 = *(const float4*)&qk_s[h * DDRUG + lane * 4];
            float p = x4.x * q4.x + x4.y * q4.y + x4.z * q4.z + x4.w * q4.w;
            #pragma unroll
            for (int off = 32; off > 0; off >>= 1) p += __shfl_xor(p, off, 64);
            if (lane == 0) s_s[m * 17 + h] = p;
        }
    }
    __syncthreads();

    // softmax: wave w handles heads 4w..4w+3; lanes cover m = lane, lane+64
    #pragma unroll
    for (int hh = 0; hh < 4; ++hh) {
        int h = w * 4 + hh;
        float v0 = (lane < n)      ? s_s[lane * 17 + h]        : -INFINITY;
        float v1 = (lane + 64 < n) ? s_s[(lane + 64) * 17 + h] : -INFINITY;
        float mx = fmaxf(v0, v1);
        #pragma unroll
        for (int off = 32; off > 0; off >>= 1) mx = fmaxf(mx, __shfl_xor(mx, off, 64));
        float e0 = (lane < n)      ? __expf(v0 - mx) : 0.f;
        float e1 = (lane + 64 < n) ? __expf(v1 - mx) : 0.f;
        float sm = e0 + e1;
        #pragma unroll
        for (int off = 32; off > 0; off >>= 1) sm += __shfl_xor(sm, off, 64);
        float inv = 1.f / sm;
        if (lane < n)      s_s[lane * 17 + h]        = e0 * inv;
        if (lane + 64 < n) s_s[(lane + 64) * 17 + h] = e1 * inv;
    }
    __syncthreads();

    // xbar: wave w owns d = w*64 + lane; X row read once per block
    const int d = w * 64 + lane;
    float acc[NH];
    #pragma unroll
    for (int h = 0; h < NH; ++h) acc[h] = 0.f;
    for (int m = 0; m < n; ++m) {
        float xr = X[(size_t)(s0 + m) * DDRUG + d];
        #pragma unroll
        for (int h = 0; h < NH; ++h) acc[h] += s_s[m * 17 + h] * xr;   // LDS broadcast
    }
    #pragma unroll
    for (int h = 0; h < NH; ++h)
        xbar[(size_t)b * (NH * DDRUG) + h * DDRUG + d] = acc[h];
}

// ---------------------------------------------------------------------------
// outh[b, h*64+j] = sum_d xbar[b,h,d] * Wv[h*64+j, d] + bv[h*64+j]
// block = (b,h); thread t: j = t>>2, quarter p = t&3; shfl-reduce over p.
// ---------------------------------------------------------------------------
__global__ __launch_bounds__(256) void outh_kernel(
    const float* __restrict__ xbar, const float* __restrict__ Wv,
    const float* __restrict__ bv, float* __restrict__ outh)
{
    __shared__ alignas(16) float xs[DDRUG];
    const int b = blockIdx.x, h = blockIdx.y, t = threadIdx.x;
    xs[t] = xbar[(size_t)b * (NH * DDRUG) + h * DDRUG + t];
    __syncthreads();
    const int j = t >> 2, p = t & 3;
    const float* wrow = &Wv[(size_t)(h * 64 + j) * DDRUG + p * 64];
    float acc = 0.f;
    #pragma unroll
    for (int i = 0; i < 16; ++i) {
        float4 w4 = *(const float4*)&wrow[i * 4];
        float4 x4 = *(const float4*)&xs[p * 64 + i * 4];
        acc += w4.x * x4.x + w4.y * x4.y + w4.z * x4.z + w4.w * x4.w;
    }
    acc += __shfl_xor(acc, 1, 64);
    acc += __shfl_xor(acc, 2, 64);
    if (p == 0) outh[(size_t)b * EMB + h * 64 + j] = acc + bv[h * 64 + j];
}

// out[:, 1024:2048] = cell
__global__ __launch_bounds__(256) void concat_kernel(
    const float* __restrict__ cell, float* __restrict__ out)
{
    const int b = blockIdx.x, t = threadIdx.x;
    *(float4*)&out[(size_t)b * 2048 + 1024 + t * 4] =
        *(const float4*)&cell[(size_t)b * DCELL + t * 4];
}

// ---------------------------------------------------------------------------
extern "C" void kernel_launch(void* const* d_in, const int* in_sizes, int n_in,
                              void* d_out, int out_size, void* d_ws, size_t ws_size,
                              hipStream_t stream)
{
    const float* x_nodes = (const float*)d_in[0];
    const float* cell    = (const float*)d_in[1];
    const float* Wq      = (const float*)d_in[2];
    const float* bq      = (const float*)d_in[3];
    const float* Wk      = (const float*)d_in[4];
    // d_in[5] = bk: provably softmax-invariant (constant per (b,h)) -> unused
    const float* Wv      = (const float*)d_in[6];
    const float* bv      = (const float*)d_in[7];
    const float* Wo      = (const float*)d_in[8];
    const float* bo      = (const float*)d_in[9];
    const float* Wc      = (const float*)d_in[10];
    const float* bc      = (const float*)d_in[11];
    const int*   guide   = (const int*)d_in[12];
    const int N = in_sizes[12];
    float* out = (float*)d_out;

    // workspace layout (~21 MB): starts | cq (reused as outh) | q | qk | xbar
    char*  ws     = (char*)d_ws;
    int*   starts = (int*)ws;
    float* cq     = (float*)(ws + 4096);
    float* qbuf   = cq   + (size_t)B_GRAPHS * EMB;
    float* qkbuf  = qbuf + (size_t)B_GRAPHS * EMB;
    float* xbar   = qkbuf + (size_t)B_GRAPHS * NH * DDRUG;

    starts_kernel<<<3, 256, 0, stream>>>(guide, N, starts);

    // cq = cell @ Wc^T + bc
    gemm_nt<<<dim3(EMB / BN, B_GRAPHS / BM), 256, 0, stream>>>(
        cell, Wc, bc, cq, DCELL, DCELL, DCELL, EMB, 1.0f);
    // q = (cq @ Wq^T + bq) * 64^-0.5
    gemm_nt<<<dim3(EMB / BN, B_GRAPHS / BM), 256, 0, stream>>>(
        cq, Wq, bq, qbuf, EMB, EMB, EMB, EMB, 0.125f);

    qk_kernel<<<dim3(B_GRAPHS / 8, NH), 256, 0, stream>>>(qbuf, Wk, qkbuf);
    attn_kernel<<<B_GRAPHS, 256, 0, stream>>>(x_nodes, qkbuf, starts, xbar);
    outh_kernel<<<dim3(B_GRAPHS, NH), 256, 0, stream>>>(xbar, Wv, bv, cq /* = outh */);

    // out[:, :1024] = outh @ Wo^T + bo   (ldc = 2048 writes into concat layout)
    gemm_nt<<<dim3(EMB / BN, B_GRAPHS / BM), 256, 0, stream>>>(
        cq, Wo, bo, out, EMB, EMB, EMB, 2048, 1.0f);
    concat_kernel<<<B_GRAPHS, 256, 0, stream>>>(cell, out);

    (void)in_sizes; (void)n_in; (void)out_size; (void)ws_size;
}

// Round 3
// 242.995 us; speedup vs baseline: 1.6555x; 1.6555x over previous
//
#include <hip/hip_runtime.h>
#include <hip/hip_bf16.h>
#include <math.h>

#define B_GRAPHS 512
#define MAXLEN   128
#define DDRUG    256
#define NH       16
#define EMB      1024

typedef __attribute__((ext_vector_type(4))) float f32x4;
typedef __attribute__((ext_vector_type(8))) short s16x8;
typedef __attribute__((ext_vector_type(4))) short s16x4;

__device__ inline short f2bf(float f) {               // RNE float->bf16
    unsigned u = __builtin_bit_cast(unsigned, f);
    u += 0x7FFF + ((u >> 16) & 1);
    return (short)(u >> 16);
}
__device__ inline float bf2f(short s) {
    unsigned u = ((unsigned)(unsigned short)s) << 16;
    return __builtin_bit_cast(float, u);
}

// ---------------------------------------------------------------------------
// starts[b] = lower_bound(guide, b); guide sorted, int32 or int64 storage.
// ---------------------------------------------------------------------------
__global__ void starts_kernel(const int* __restrict__ g32, int N, int* __restrict__ starts)
{
    int b = blockIdx.x * blockDim.x + threadIdx.x;
    if (b > B_GRAPHS) return;
    bool is64 = (g32[N - 1] == 0);                    // odd index: int64 high word
    int lo = 0, hi = N;
    while (lo < hi) {
        int mid = (lo + hi) >> 1;
        int v = is64 ? g32[2 * mid] : g32[mid];
        if (v < b) lo = mid + 1; else hi = mid;
    }
    starts[b] = lo;
}

// fp32 -> bf16 bulk convert (n4 = element count / 4)
__global__ __launch_bounds__(256) void cvt_bf16(
    const float* __restrict__ in, short* __restrict__ out, int n4)
{
    int i = blockIdx.x * 256 + threadIdx.x;
    int stride = gridDim.x * 256;
    for (; i < n4; i += stride) {
        f32x4 v = ((const f32x4*)in)[i];
        s16x4 o;
        o.x = f2bf(v.x); o.y = f2bf(v.y); o.z = f2bf(v.z); o.w = f2bf(v.w);
        ((s16x4*)out)[i] = o;
    }
}

// ---------------------------------------------------------------------------
// C[M,N] = (A[M,K] * B[N,K]^T + bias[N]) * scale, A/B bf16, K=1024.
// BM=BN=64, BK=64; 4 waves (2x2), each 32x32 via 16x16x32 MFMA.
// LDS rows XOR-swizzled by ((row&7)<<4) for conflict-free ds_read_b128.
// ---------------------------------------------------------------------------
template<bool OUT_BF>
__global__ __launch_bounds__(256) void gemm_bf16_nt(
    const short* __restrict__ A, int lda,
    const short* __restrict__ Bw, int ldb,
    const float* __restrict__ bias, void* __restrict__ Cout,
    int ldc, float scale)
{
    __shared__ short As[64 * 64];
    __shared__ short Bs[64 * 64];
    const int t = threadIdx.x, lane = t & 63, w = t >> 6;
    const int wm = w >> 1, wn = w & 1;
    const int row0 = blockIdx.y * 64, col0 = blockIdx.x * 64;
    f32x4 c[2][2] = {};

    const int sr = t >> 2, sc = (t & 3) * 16;         // staging: row, col (bf16 elems)
    const int swz = (sr & 7) << 4;
    const int kb0 = (lane >> 4) * 8;

    for (int kt = 0; kt < 1024; kt += 64) {
        s16x8 va0 = *(const s16x8*)&A [(size_t)(row0 + sr) * lda + kt + sc];
        s16x8 va1 = *(const s16x8*)&A [(size_t)(row0 + sr) * lda + kt + sc + 8];
        s16x8 vb0 = *(const s16x8*)&Bw[(size_t)(col0 + sr) * ldb + kt + sc];
        s16x8 vb1 = *(const s16x8*)&Bw[(size_t)(col0 + sr) * ldb + kt + sc + 8];
        *(s16x8*)((char*)As + sr * 128 + ((sc * 2)      ^ swz)) = va0;
        *(s16x8*)((char*)As + sr * 128 + ((sc * 2 + 16) ^ swz)) = va1;
        *(s16x8*)((char*)Bs + sr * 128 + ((sc * 2)      ^ swz)) = vb0;
        *(s16x8*)((char*)Bs + sr * 128 + ((sc * 2 + 16) ^ swz)) = vb1;
        __syncthreads();
        #pragma unroll
        for (int ks = 0; ks < 2; ++ks) {
            const int kk = (ks * 32 + kb0) * 2;       // byte offset within row
            s16x8 a0, a1, b0, b1;
            {
                int r = wm * 32 + (lane & 15);
                a0 = *(const s16x8*)((char*)As + r * 128 + (kk ^ ((r & 7) << 4)));
                int r2 = r + 16;
                a1 = *(const s16x8*)((char*)As + r2 * 128 + (kk ^ ((r2 & 7) << 4)));
            }
            {
                int r = wn * 32 + (lane & 15);
                b0 = *(const s16x8*)((char*)Bs + r * 128 + (kk ^ ((r & 7) << 4)));
                int r2 = r + 16;
                b1 = *(const s16x8*)((char*)Bs + r2 * 128 + (kk ^ ((r2 & 7) << 4)));
            }
            c[0][0] = __builtin_amdgcn_mfma_f32_16x16x32_bf16(a0, b0, c[0][0], 0, 0, 0);
            c[0][1] = __builtin_amdgcn_mfma_f32_16x16x32_bf16(a0, b1, c[0][1], 0, 0, 0);
            c[1][0] = __builtin_amdgcn_mfma_f32_16x16x32_bf16(a1, b0, c[1][0], 0, 0, 0);
            c[1][1] = __builtin_amdgcn_mfma_f32_16x16x32_bf16(a1, b1, c[1][1], 0, 0, 0);
        }
        __syncthreads();
    }
    #pragma unroll
    for (int i = 0; i < 2; ++i)
    #pragma unroll
    for (int j = 0; j < 2; ++j) {
        int m0 = row0 + wm * 32 + i * 16 + (lane >> 4) * 4;
        int nn = col0 + wn * 32 + j * 16 + (lane & 15);
        #pragma unroll
        for (int r = 0; r < 4; ++r) {
            float v = (c[i][j][r] + bias[nn]) * scale;
            if (OUT_BF) ((short*)Cout)[(size_t)(m0 + r) * ldc + nn] = f2bf(v);
            else        ((float*)Cout)[(size_t)(m0 + r) * ldc + nn] = v;
        }
    }
}

// ---------------------------------------------------------------------------
// qk[b, h, d] = sum_j q[b, h*64+j] * Wk[h*64+j, d]   (fp32 in, bf16 out)
// ---------------------------------------------------------------------------
__global__ __launch_bounds__(256) void qk_kernel(
    const float* __restrict__ q, const float* __restrict__ Wk, short* __restrict__ qkout)
{
    __shared__ float q_s[8][64];
    const int bt = blockIdx.x, h = blockIdx.y, t = threadIdx.x;
    for (int i = t; i < 512; i += 256)
        q_s[i >> 6][i & 63] = q[(size_t)(bt * 8 + (i >> 6)) * EMB + h * 64 + (i & 63)];
    __syncthreads();
    float acc[8] = {};
    const float* wbase = &Wk[(size_t)h * 64 * DDRUG + t];
    #pragma unroll 4
    for (int j = 0; j < 64; ++j) {
        float wv = wbase[(size_t)j * DDRUG];
        #pragma unroll
        for (int bb = 0; bb < 8; ++bb) acc[bb] += q_s[bb][j] * wv;
    }
    #pragma unroll
    for (int bb = 0; bb < 8; ++bb)
        qkout[(size_t)(bt * 8 + bb) * 4096 + h * DDRUG + t] = f2bf(acc[bb]);
}

// ---------------------------------------------------------------------------
// Per-graph attention. Scores via MFMA (S^T = qk . X^T), softmax on VALU,
// xbar (attn-weighted X average) via unrolled VALU, output bf16.
// ---------------------------------------------------------------------------
__global__ __launch_bounds__(256) void attn_kernel(
    const float* __restrict__ X, const short* __restrict__ qk,
    const int* __restrict__ starts, short* __restrict__ xbar, int Ntot)
{
    __shared__ short qk_s[16 * 256];     // swizzled bf16
    __shared__ short Xs[64 * 256];       // swizzled bf16, one 64-row stage
    __shared__ float S_s[128 * 20];      // scores/attn, pitch 20 (16B-aligned rows)
    const int b = blockIdx.x, t = threadIdx.x;
    const int lane = t & 63, w = t >> 6;
    const int s0 = starts[b];
    int n = starts[b + 1] - s0;
    if (n > MAXLEN) n = MAXLEN;

    // stage qk: bf16 global -> swizzled LDS (rows = heads)
    {
        int h = t >> 4, cc = (t & 15) * 16;
        const s16x8* src = (const s16x8*)(qk + (size_t)b * 4096 + h * 256 + cc);
        int swzh = (h & 7) << 4;
        *(s16x8*)((char*)qk_s + h * 512 + ((cc * 2)      ^ swzh)) = src[0];
        *(s16x8*)((char*)qk_s + h * 512 + ((cc * 2 + 16) ^ swzh)) = src[1];
    }

    const int sr = t >> 2, scg = (t & 3) * 64;        // X staging: row, col group
    auto stageX = [&](int st) {
        int gm = s0 + st * 64 + sr;
        if (gm > Ntot - 1) gm = Ntot - 1;             // clamp (rows >= n are masked)
        const f32x4* src = (const f32x4*)(X + (size_t)gm * 256 + scg);
        int swzr = (sr & 7) << 4;
        #pragma unroll
        for (int j = 0; j < 8; ++j) {
            f32x4 a = src[2 * j], bb = src[2 * j + 1];
            s16x8 v;
            v[0] = f2bf(a.x);  v[1] = f2bf(a.y);  v[2] = f2bf(a.z);  v[3] = f2bf(a.w);
            v[4] = f2bf(bb.x); v[5] = f2bf(bb.y); v[6] = f2bf(bb.z); v[7] = f2bf(bb.w);
            *(s16x8*)((char*)Xs + sr * 512 + (((scg + j * 8) * 2) ^ swzr)) = v;
        }
    };
    stageX(0);
    __syncthreads();

    // A-fragments (qk) into registers: A[r=h][k=d]
    s16x8 af[8];
    {
        int h = lane & 15, swzh = (h & 7) << 4;
        #pragma unroll
        for (int ks = 0; ks < 8; ++ks) {
            int k = ks * 32 + (lane >> 4) * 8;
            af[ks] = *(const s16x8*)((char*)qk_s + h * 512 + ((k * 2) ^ swzh));
        }
    }
    // S^T MFMA: wave w owns local rows [w*16, w*16+16); K=256 over 8 steps
    auto mfmaStage = [&](int st) {
        int lr = w * 16 + (lane & 15);
        int swzr = (lr & 7) << 4;
        f32x4 c = {0.f, 0.f, 0.f, 0.f};
        #pragma unroll
        for (int ks = 0; ks < 8; ++ks) {
            int k = ks * 32 + (lane >> 4) * 8;
            s16x8 bf = *(const s16x8*)((char*)Xs + lr * 512 + ((k * 2) ^ swzr));
            c = __builtin_amdgcn_mfma_f32_16x16x32_bf16(af[ks], bf, c, 0, 0, 0);
        }
        int m = st * 64 + w * 16 + (lane & 15);
        int hb = (lane >> 4) * 4;                     // D: row=(lane>>4)*4+i (=h), col=lane&15 (=m)
        #pragma unroll
        for (int i = 0; i < 4; ++i) S_s[m * 20 + hb + i] = c[i];
    };
    mfmaStage(0);
    if (n > 64) {                                     // block-uniform branch
        __syncthreads();
        stageX(1);
        __syncthreads();
        mfmaStage(1);
    }
    __syncthreads();

    // masked softmax; wave w handles heads 4w..4w+3
    #pragma unroll
    for (int hh = 0; hh < 4; ++hh) {
        int h = w * 4 + hh;
        float v0 = (lane < n)      ? S_s[lane * 20 + h]        : -INFINITY;
        float v1 = (lane + 64 < n) ? S_s[(lane + 64) * 20 + h] : -INFINITY;
        float mx = fmaxf(v0, v1);
        #pragma unroll
        for (int off = 32; off > 0; off >>= 1) mx = fmaxf(mx, __shfl_xor(mx, off, 64));
        float e0 = (lane < n)      ? __expf(v0 - mx) : 0.f;
        float e1 = (lane + 64 < n) ? __expf(v1 - mx) : 0.f;
        float sm = e0 + e1;
        #pragma unroll
        for (int off = 32; off > 0; off >>= 1) sm += __shfl_xor(sm, off, 64);
        float inv = 1.f / sm;
        if (lane < n)      S_s[lane * 20 + h]        = e0 * inv;
        if (lane + 64 < n) S_s[(lane + 64) * 20 + h] = e1 * inv;
    }
    __syncthreads();

    // xbar[h][d] = sum_m P[m][h] * X[m][d]; thread owns d = t, 4x unrolled
    const int d = t;
    float acc[16] = {};
    const float* Xb = X + (size_t)s0 * 256 + d;
    int m = 0;
    for (; m + 4 <= n; m += 4) {
        float xv[4];
        #pragma unroll
        for (int u = 0; u < 4; ++u) xv[u] = Xb[(size_t)(m + u) * 256];
        #pragma unroll
        for (int u = 0; u < 4; ++u) {
            const f32x4* prow = (const f32x4*)&S_s[(m + u) * 20];
            f32x4 p0 = prow[0], p1 = prow[1], p2 = prow[2], p3 = prow[3];
            float x = xv[u];
            acc[0] += p0.x * x; acc[1] += p0.y * x; acc[2]  += p0.z * x; acc[3]  += p0.w * x;
            acc[4] += p1.x * x; acc[5] += p1.y * x; acc[6]  += p1.z * x; acc[7]  += p1.w * x;
            acc[8] += p2.x * x; acc[9] += p2.y * x; acc[10] += p2.z * x; acc[11] += p2.w * x;
            acc[12] += p3.x * x; acc[13] += p3.y * x; acc[14] += p3.z * x; acc[15] += p3.w * x;
        }
    }
    for (; m < n; ++m) {
        const f32x4* prow = (const f32x4*)&S_s[m * 20];
        f32x4 p0 = prow[0], p1 = prow[1], p2 = prow[2], p3 = prow[3];
        float x = Xb[(size_t)m * 256];
        acc[0] += p0.x * x; acc[1] += p0.y * x; acc[2]  += p0.z * x; acc[3]  += p0.w * x;
        acc[4] += p1.x * x; acc[5] += p1.y * x; acc[6]  += p1.z * x; acc[7]  += p1.w * x;
        acc[8] += p2.x * x; acc[9] += p2.y * x; acc[10] += p2.z * x; acc[11] += p2.w * x;
        acc[12] += p3.x * x; acc[13] += p3.y * x; acc[14] += p3.z * x; acc[15] += p3.w * x;
    }
    short* xb = xbar + (size_t)b * 4096 + d;
    #pragma unroll
    for (int h = 0; h < 16; ++h) xb[(size_t)h * 256] = f2bf(acc[h]);
}

// ---------------------------------------------------------------------------
// outh[b, h*64+j] = sum_d xbar[b,h,d] * Wv[h*64+j, d] + bv  (bf16 in/out)
// ---------------------------------------------------------------------------
__global__ __launch_bounds__(256) void outh_kernel(
    const short* __restrict__ xbar, const float* __restrict__ Wv,
    const float* __restrict__ bv, short* __restrict__ outh)
{
    __shared__ float xs[DDRUG];
    const int b = blockIdx.x, h = blockIdx.y, t = threadIdx.x;
    xs[t] = bf2f(xbar[(size_t)b * 4096 + h * DDRUG + t]);
    __syncthreads();
    const int j = t >> 2, p = t & 3;
    const float* wrow = &Wv[(size_t)(h * 64 + j) * DDRUG + p * 64];
    float acc = 0.f;
    #pragma unroll
    for (int i = 0; i < 16; ++i) {
        f32x4 w4 = *(const f32x4*)&wrow[i * 4];
        f32x4 x4 = *(const f32x4*)&xs[p * 64 + i * 4];
        acc += w4.x * x4.x + w4.y * x4.y + w4.z * x4.z + w4.w * x4.w;
    }
    acc += __shfl_xor(acc, 1, 64);
    acc += __shfl_xor(acc, 2, 64);
    if (p == 0) outh[(size_t)b * EMB + h * 64 + j] = f2bf(acc + bv[h * 64 + j]);
}

// out[:, 1024:2048] = cell
__global__ __launch_bounds__(256) void concat_kernel(
    const float* __restrict__ cell, float* __restrict__ out)
{
    const int b = blockIdx.x, t = threadIdx.x;
    *(f32x4*)&out[(size_t)b * 2048 + 1024 + t * 4] =
        *(const f32x4*)&cell[(size_t)b * 1024 + t * 4];
}

// ---------------------------------------------------------------------------
extern "C" void kernel_launch(void* const* d_in, const int* in_sizes, int n_in,
                              void* d_out, int out_size, void* d_ws, size_t ws_size,
                              hipStream_t stream)
{
    const float* x_nodes = (const float*)d_in[0];
    const float* cell    = (const float*)d_in[1];
    const float* Wq      = (const float*)d_in[2];
    const float* bq      = (const float*)d_in[3];
    const float* Wk      = (const float*)d_in[4];
    // d_in[5] = bk: softmax-invariant, dropped
    const float* Wv      = (const float*)d_in[6];
    const float* bv      = (const float*)d_in[7];
    const float* Wo      = (const float*)d_in[8];
    const float* bo      = (const float*)d_in[9];
    const float* Wc      = (const float*)d_in[10];
    const float* bc      = (const float*)d_in[11];
    const int*   guide   = (const int*)d_in[12];
    const int N = in_sizes[12];
    float* out = (float*)d_out;

    // workspace layout (19.0 MB; harness provides >= 20.9 MB per round-1 run)
    char* ws = (char*)d_ws;
    int*   starts  = (int*)ws;
    float* qf32    = (float*)(ws + 4096);                    // 2 MB
    short* cell_bf = (short*)(ws + 4096 + (2u << 20));       // 1 MB
    short* cq_bf   = (short*)(ws + 4096 + (3u << 20));       // 1 MB
    short* outh_bf = (short*)(ws + 4096 + (4u << 20));       // 1 MB
    short* qk_bf   = (short*)(ws + 4096 + (5u << 20));       // 4 MB
    short* xbar_bf = (short*)(ws + 4096 + (9u << 20));       // 4 MB
    short* Wc_bf   = (short*)(ws + 4096 + (13u << 20));      // 2 MB
    short* Wq_bf   = (short*)(ws + 4096 + (15u << 20));      // 2 MB
    short* Wo_bf   = (short*)(ws + 4096 + (17u << 20));      // 2 MB

    starts_kernel<<<3, 256, 0, stream>>>(guide, N, starts);
    cvt_bf16<<<512, 256, 0, stream>>>(cell, cell_bf, (512 * 1024) / 4);
    cvt_bf16<<<512, 256, 0, stream>>>(Wc, Wc_bf, (1024 * 1024) / 4);
    cvt_bf16<<<512, 256, 0, stream>>>(Wq, Wq_bf, (1024 * 1024) / 4);
    cvt_bf16<<<512, 256, 0, stream>>>(Wo, Wo_bf, (1024 * 1024) / 4);

    // cq = cell @ Wc^T + bc           (bf16 out)
    gemm_bf16_nt<true ><<<dim3(16, 8), 256, 0, stream>>>(
        cell_bf, 1024, Wc_bf, 1024, bc, cq_bf, 1024, 1.0f);
    // q = (cq @ Wq^T + bq) * 0.125    (fp32 out)
    gemm_bf16_nt<false><<<dim3(16, 8), 256, 0, stream>>>(
        cq_bf, 1024, Wq_bf, 1024, bq, qf32, 1024, 0.125f);

    qk_kernel<<<dim3(B_GRAPHS / 8, NH), 256, 0, stream>>>(qf32, Wk, qk_bf);
    attn_kernel<<<B_GRAPHS, 256, 0, stream>>>(x_nodes, qk_bf, starts, xbar_bf, N);
    outh_kernel<<<dim3(B_GRAPHS, NH), 256, 0, stream>>>(xbar_bf, Wv, bv, outh_bf);

    // out[:, :1024] = outh @ Wo^T + bo  (fp32, ldc=2048 -> concat layout)
    gemm_bf16_nt<false><<<dim3(16, 8), 256, 0, stream>>>(
        outh_bf, 1024, Wo_bf, 1024, bo, out, 2048, 1.0f);
    concat_kernel<<<B_GRAPHS, 256, 0, stream>>>(cell, out);

    (void)in_sizes; (void)n_in; (void)out_size; (void)ws_size;
}

// Round 6
// 186.459 us; speedup vs baseline: 2.1574x; 1.3032x over previous
//
#include <hip/hip_runtime.h>
#include <hip/hip_bf16.h>
#include <math.h>

#define B_GRAPHS 512
#define MAXLEN   128
#define DDRUG    256
#define NH       16
#define EMB      1024

typedef __attribute__((ext_vector_type(4))) float f32x4;
typedef __attribute__((ext_vector_type(8))) short s16x8;
typedef __attribute__((ext_vector_type(4))) short s16x4;

__device__ inline short f2bf(float f) {               // RNE float->bf16
    unsigned u = __builtin_bit_cast(unsigned, f);
    u += 0x7FFF + ((u >> 16) & 1);
    return (short)(u >> 16);
}
__device__ inline float bf2f(short s) {
    unsigned u = ((unsigned)(unsigned short)s) << 16;
    return __builtin_bit_cast(float, u);
}

// ---------------------------------------------------------------------------
// starts[b] = lower_bound(guide, b); guide sorted, int32 or int64 storage.
// ---------------------------------------------------------------------------
__global__ void starts_kernel(const int* __restrict__ g32, int N, int* __restrict__ starts)
{
    int b = blockIdx.x * blockDim.x + threadIdx.x;
    if (b > B_GRAPHS) return;
    bool is64 = (g32[N - 1] == 0);                    // odd index: int64 high word
    int lo = 0, hi = N;
    while (lo < hi) {
        int mid = (lo + hi) >> 1;
        int v = is64 ? g32[2 * mid] : g32[mid];
        if (v < b) lo = mid + 1; else hi = mid;
    }
    starts[b] = lo;
}

// fp32 -> bf16 bulk convert (n4 = element count / 4)
__global__ __launch_bounds__(256) void cvt_bf16(
    const float* __restrict__ in, short* __restrict__ out, int n4)
{
    int i = blockIdx.x * 256 + threadIdx.x;
    int stride = gridDim.x * 256;
    for (; i < n4; i += stride) {
        f32x4 v = ((const f32x4*)in)[i];
        s16x4 o;
        o.x = f2bf(v.x); o.y = f2bf(v.y); o.z = f2bf(v.z); o.w = f2bf(v.w);
        ((s16x4*)out)[i] = o;
    }
}

// ---------------------------------------------------------------------------
// C[M,N] = (A[M,K] * B[N,K]^T + bias[N]) * scale, A/B bf16, K=1024.
// BM=BN=64, BK=64; 4 waves (2x2), each 32x32 via 16x16x32 MFMA.
// LDS rows XOR-swizzled by ((row&7)<<4) for conflict-free ds_read_b128.
// ---------------------------------------------------------------------------
template<bool OUT_BF>
__global__ __launch_bounds__(256) void gemm_bf16_nt(
    const short* __restrict__ A, int lda,
    const short* __restrict__ Bw, int ldb,
    const float* __restrict__ bias, void* __restrict__ Cout,
    int ldc, float scale)
{
    __shared__ short As[64 * 64];
    __shared__ short Bs[64 * 64];
    const int t = threadIdx.x, lane = t & 63, w = t >> 6;
    const int wm = w >> 1, wn = w & 1;
    const int row0 = blockIdx.y * 64, col0 = blockIdx.x * 64;
    f32x4 c[2][2] = {};

    const int sr = t >> 2, sc = (t & 3) * 16;         // staging: row, col (bf16 elems)
    const int swz = (sr & 7) << 4;
    const int kb0 = (lane >> 4) * 8;

    for (int kt = 0; kt < 1024; kt += 64) {
        s16x8 va0 = *(const s16x8*)&A [(size_t)(row0 + sr) * lda + kt + sc];
        s16x8 va1 = *(const s16x8*)&A [(size_t)(row0 + sr) * lda + kt + sc + 8];
        s16x8 vb0 = *(const s16x8*)&Bw[(size_t)(col0 + sr) * ldb + kt + sc];
        s16x8 vb1 = *(const s16x8*)&Bw[(size_t)(col0 + sr) * ldb + kt + sc + 8];
        *(s16x8*)((char*)As + sr * 128 + ((sc * 2)      ^ swz)) = va0;
        *(s16x8*)((char*)As + sr * 128 + ((sc * 2 + 16) ^ swz)) = va1;
        *(s16x8*)((char*)Bs + sr * 128 + ((sc * 2)      ^ swz)) = vb0;
        *(s16x8*)((char*)Bs + sr * 128 + ((sc * 2 + 16) ^ swz)) = vb1;
        __syncthreads();
        #pragma unroll
        for (int ks = 0; ks < 2; ++ks) {
            const int kk = (ks * 32 + kb0) * 2;       // byte offset within row
            s16x8 a0, a1, b0, b1;
            {
                int r = wm * 32 + (lane & 15);
                a0 = *(const s16x8*)((char*)As + r * 128 + (kk ^ ((r & 7) << 4)));
                int r2 = r + 16;
                a1 = *(const s16x8*)((char*)As + r2 * 128 + (kk ^ ((r2 & 7) << 4)));
            }
            {
                int r = wn * 32 + (lane & 15);
                b0 = *(const s16x8*)((char*)Bs + r * 128 + (kk ^ ((r & 7) << 4)));
                int r2 = r + 16;
                b1 = *(const s16x8*)((char*)Bs + r2 * 128 + (kk ^ ((r2 & 7) << 4)));
            }
            c[0][0] = __builtin_amdgcn_mfma_f32_16x16x32_bf16(a0, b0, c[0][0], 0, 0, 0);
            c[0][1] = __builtin_amdgcn_mfma_f32_16x16x32_bf16(a0, b1, c[0][1], 0, 0, 0);
            c[1][0] = __builtin_amdgcn_mfma_f32_16x16x32_bf16(a1, b0, c[1][0], 0, 0, 0);
            c[1][1] = __builtin_amdgcn_mfma_f32_16x16x32_bf16(a1, b1, c[1][1], 0, 0, 0);
        }
        __syncthreads();
    }
    #pragma unroll
    for (int i = 0; i < 2; ++i)
    #pragma unroll
    for (int j = 0; j < 2; ++j) {
        int m0 = row0 + wm * 32 + i * 16 + (lane >> 4) * 4;
        int nn = col0 + wn * 32 + j * 16 + (lane & 15);
        #pragma unroll
        for (int r = 0; r < 4; ++r) {
            float v = (c[i][j][r] + bias[nn]) * scale;
            if (OUT_BF) ((short*)Cout)[(size_t)(m0 + r) * ldc + nn] = f2bf(v);
            else        ((float*)Cout)[(size_t)(m0 + r) * ldc + nn] = v;
        }
    }
}

// ---------------------------------------------------------------------------
// qk[b, h, d] = sum_j q[b, h*64+j] * Wk[h*64+j, d]   (fp32 in, bf16 out)
// ---------------------------------------------------------------------------
__global__ __launch_bounds__(256) void qk_kernel(
    const float* __restrict__ q, const float* __restrict__ Wk, short* __restrict__ qkout)
{
    __shared__ float q_s[8][64];
    const int bt = blockIdx.x, h = blockIdx.y, t = threadIdx.x;
    for (int i = t; i < 512; i += 256)
        q_s[i >> 6][i & 63] = q[(size_t)(bt * 8 + (i >> 6)) * EMB + h * 64 + (i & 63)];
    __syncthreads();
    float acc[8] = {};
    const float* wbase = &Wk[(size_t)h * 64 * DDRUG + t];
    #pragma unroll 4
    for (int j = 0; j < 64; ++j) {
        float wv = wbase[(size_t)j * DDRUG];
        #pragma unroll
        for (int bb = 0; bb < 8; ++bb) acc[bb] += q_s[bb][j] * wv;
    }
    #pragma unroll
    for (int bb = 0; bb < 8; ++bb)
        qkout[(size_t)(bt * 8 + bb) * 4096 + h * DDRUG + t] = f2bf(acc[bb]);
}

// ---------------------------------------------------------------------------
// Per-graph attention. Scores via MFMA (S^T = qk . X^T), softmax on VALU,
// xbar (attn-weighted X average) via unrolled VALU, output bf16.
// ---------------------------------------------------------------------------
__global__ __launch_bounds__(256) void attn_kernel(
    const float* __restrict__ X, const short* __restrict__ qk,
    const int* __restrict__ starts, short* __restrict__ xbar, int Ntot)
{
    __shared__ short qk_s[16 * 256];     // swizzled bf16
    __shared__ short Xs[64 * 256];       // swizzled bf16, one 64-row stage
    __shared__ float S_s[128 * 20];      // scores/attn, pitch 20 (16B-aligned rows)
    const int b = blockIdx.x, t = threadIdx.x;
    const int lane = t & 63, w = t >> 6;
    const int s0 = starts[b];
    int n = starts[b + 1] - s0;
    if (n > MAXLEN) n = MAXLEN;

    // stage qk: bf16 global -> swizzled LDS (rows = heads)
    {
        int h = t >> 4, cc = (t & 15) * 16;
        const s16x8* src = (const s16x8*)(qk + (size_t)b * 4096 + h * 256 + cc);
        int swzh = (h & 7) << 4;
        *(s16x8*)((char*)qk_s + h * 512 + ((cc * 2)      ^ swzh)) = src[0];
        *(s16x8*)((char*)qk_s + h * 512 + ((cc * 2 + 16) ^ swzh)) = src[1];
    }

    const int sr = t >> 2, scg = (t & 3) * 64;        // X staging: row, col group
    auto stageX = [&](int st) {
        int gm = s0 + st * 64 + sr;
        if (gm > Ntot - 1) gm = Ntot - 1;             // clamp (rows >= n are masked)
        const f32x4* src = (const f32x4*)(X + (size_t)gm * 256 + scg);
        int swzr = (sr & 7) << 4;
        #pragma unroll
        for (int j = 0; j < 8; ++j) {
            f32x4 a = src[2 * j], bb = src[2 * j + 1];
            s16x8 v;
            v[0] = f2bf(a.x);  v[1] = f2bf(a.y);  v[2] = f2bf(a.z);  v[3] = f2bf(a.w);
            v[4] = f2bf(bb.x); v[5] = f2bf(bb.y); v[6] = f2bf(bb.z); v[7] = f2bf(bb.w);
            *(s16x8*)((char*)Xs + sr * 512 + (((scg + j * 8) * 2) ^ swzr)) = v;
        }
    };
    stageX(0);
    __syncthreads();

    // A-fragments (qk) into registers: A[r=h][k=d]
    s16x8 af[8];
    {
        int h = lane & 15, swzh = (h & 7) << 4;
        #pragma unroll
        for (int ks = 0; ks < 8; ++ks) {
            int k = ks * 32 + (lane >> 4) * 8;
            af[ks] = *(const s16x8*)((char*)qk_s + h * 512 + ((k * 2) ^ swzh));
        }
    }
    // S^T MFMA: wave w owns local rows [w*16, w*16+16); K=256 over 8 steps
    auto mfmaStage = [&](int st) {
        int lr = w * 16 + (lane & 15);
        int swzr = (lr & 7) << 4;
        f32x4 c = {0.f, 0.f, 0.f, 0.f};
        #pragma unroll
        for (int ks = 0; ks < 8; ++ks) {
            int k = ks * 32 + (lane >> 4) * 8;
            s16x8 bf = *(const s16x8*)((char*)Xs + lr * 512 + ((k * 2) ^ swzr));
            c = __builtin_amdgcn_mfma_f32_16x16x32_bf16(af[ks], bf, c, 0, 0, 0);
        }
        int m = st * 64 + w * 16 + (lane & 15);
        int hb = (lane >> 4) * 4;                     // D: row=(lane>>4)*4+i (=h), col=lane&15 (=m)
        #pragma unroll
        for (int i = 0; i < 4; ++i) S_s[m * 20 + hb + i] = c[i];
    };
    mfmaStage(0);
    if (n > 64) {                                     // block-uniform branch
        __syncthreads();
        stageX(1);
        __syncthreads();
        mfmaStage(1);
    }
    __syncthreads();

    // masked softmax; wave w handles heads 4w..4w+3
    #pragma unroll
    for (int hh = 0; hh < 4; ++hh) {
        int h = w * 4 + hh;
        float v0 = (lane < n)      ? S_s[lane * 20 + h]        : -INFINITY;
        float v1 = (lane + 64 < n) ? S_s[(lane + 64) * 20 + h] : -INFINITY;
        float mx = fmaxf(v0, v1);
        #pragma unroll
        for (int off = 32; off > 0; off >>= 1) mx = fmaxf(mx, __shfl_xor(mx, off, 64));
        float e0 = (lane < n)      ? __expf(v0 - mx) : 0.f;
        float e1 = (lane + 64 < n) ? __expf(v1 - mx) : 0.f;
        float sm = e0 + e1;
        #pragma unroll
        for (int off = 32; off > 0; off >>= 1) sm += __shfl_xor(sm, off, 64);
        float inv = 1.f / sm;
        if (lane < n)      S_s[lane * 20 + h]        = e0 * inv;
        if (lane + 64 < n) S_s[(lane + 64) * 20 + h] = e1 * inv;
    }
    __syncthreads();

    // xbar[h][d] = sum_m P[m][h] * X[m][d]; thread owns d = t, 4x unrolled
    const int d = t;
    float acc[16] = {};
    const float* Xb = X + (size_t)s0 * 256 + d;
    int m = 0;
    for (; m + 4 <= n; m += 4) {
        float xv[4];
        #pragma unroll
        for (int u = 0; u < 4; ++u) xv[u] = Xb[(size_t)(m + u) * 256];
        #pragma unroll
        for (int u = 0; u < 4; ++u) {
            const f32x4* prow = (const f32x4*)&S_s[(m + u) * 20];
            f32x4 p0 = prow[0], p1 = prow[1], p2 = prow[2], p3 = prow[3];
            float x = xv[u];
            acc[0] += p0.x * x; acc[1] += p0.y * x; acc[2]  += p0.z * x; acc[3]  += p0.w * x;
            acc[4] += p1.x * x; acc[5] += p1.y * x; acc[6]  += p1.z * x; acc[7]  += p1.w * x;
            acc[8] += p2.x * x; acc[9] += p2.y * x; acc[10] += p2.z * x; acc[11] += p2.w * x;
            acc[12] += p3.x * x; acc[13] += p3.y * x; acc[14] += p3.z * x; acc[15] += p3.w * x;
        }
    }
    for (; m < n; ++m) {
        const f32x4* prow = (const f32x4*)&S_s[m * 20];
        f32x4 p0 = prow[0], p1 = prow[1], p2 = prow[2], p3 = prow[3];
        float x = Xb[(size_t)m * 256];
        acc[0] += p0.x * x; acc[1] += p0.y * x; acc[2]  += p0.z * x; acc[3]  += p0.w * x;
        acc[4] += p1.x * x; acc[5] += p1.y * x; acc[6]  += p1.z * x; acc[7]  += p1.w * x;
        acc[8] += p2.x * x; acc[9] += p2.y * x; acc[10] += p2.z * x; acc[11] += p2.w * x;
        acc[12] += p3.x * x; acc[13] += p3.y * x; acc[14] += p3.z * x; acc[15] += p3.w * x;
    }
    short* xb = xbar + (size_t)b * 4096 + d;
    #pragma unroll
    for (int h = 0; h < 16; ++h) xb[(size_t)h * 256] = f2bf(acc[h]);
}

// ---------------------------------------------------------------------------
// outh: per-head mini-GEMM.  outh[b, h*64+j] = sum_d xbar[b,h,d]*Wv[h*64+j,d] + bv
// grid = (8 b-tiles, 16 heads); 64x64 output tile, K=256 over 4 LDS stages.
// Replaces the latency-bound matvec version (66 us: 4-way LDS bank conflicts,
// 512x redundant Wv reads, VALU-only).
// ---------------------------------------------------------------------------
__global__ __launch_bounds__(256) void outh_gemm(
    const short* __restrict__ xbar,   // [512][4096] bf16, head h at cols h*256..
    const short* __restrict__ Wv_bf,  // [1024][256] bf16
    const float* __restrict__ bv, short* __restrict__ outh)
{
    __shared__ short As[64 * 64];
    __shared__ short Bs[64 * 64];
    const int t = threadIdx.x, lane = t & 63, w = t >> 6;
    const int wm = w >> 1, wn = w & 1;
    const int h = blockIdx.y;
    const int row0 = blockIdx.x * 64;                 // b tile
    const short* A = xbar + (size_t)h * 256;          // row stride 4096
    const short* B = Wv_bf + (size_t)h * 64 * 256;    // row stride 256
    f32x4 c[2][2] = {};

    const int sr = t >> 2, sc = (t & 3) * 16;
    const int swz = (sr & 7) << 4;
    const int kb0 = (lane >> 4) * 8;

    for (int kt = 0; kt < 256; kt += 64) {
        s16x8 va0 = *(const s16x8*)&A[(size_t)(row0 + sr) * 4096 + kt + sc];
        s16x8 va1 = *(const s16x8*)&A[(size_t)(row0 + sr) * 4096 + kt + sc + 8];
        s16x8 vb0 = *(const s16x8*)&B[(size_t)sr * 256 + kt + sc];
        s16x8 vb1 = *(const s16x8*)&B[(size_t)sr * 256 + kt + sc + 8];
        *(s16x8*)((char*)As + sr * 128 + ((sc * 2)      ^ swz)) = va0;
        *(s16x8*)((char*)As + sr * 128 + ((sc * 2 + 16) ^ swz)) = va1;
        *(s16x8*)((char*)Bs + sr * 128 + ((sc * 2)      ^ swz)) = vb0;
        *(s16x8*)((char*)Bs + sr * 128 + ((sc * 2 + 16) ^ swz)) = vb1;
        __syncthreads();
        #pragma unroll
        for (int ks = 0; ks < 2; ++ks) {
            const int kk = (ks * 32 + kb0) * 2;
            s16x8 a0, a1, b0, b1;
            {
                int r = wm * 32 + (lane & 15);
                a0 = *(const s16x8*)((char*)As + r * 128 + (kk ^ ((r & 7) << 4)));
                int r2 = r + 16;
                a1 = *(const s16x8*)((char*)As + r2 * 128 + (kk ^ ((r2 & 7) << 4)));
            }
            {
                int r = wn * 32 + (lane & 15);
                b0 = *(const s16x8*)((char*)Bs + r * 128 + (kk ^ ((r & 7) << 4)));
                int r2 = r + 16;
                b1 = *(const s16x8*)((char*)Bs + r2 * 128 + (kk ^ ((r2 & 7) << 4)));
            }
            c[0][0] = __builtin_amdgcn_mfma_f32_16x16x32_bf16(a0, b0, c[0][0], 0, 0, 0);
            c[0][1] = __builtin_amdgcn_mfma_f32_16x16x32_bf16(a0, b1, c[0][1], 0, 0, 0);
            c[1][0] = __builtin_amdgcn_mfma_f32_16x16x32_bf16(a1, b0, c[1][0], 0, 0, 0);
            c[1][1] = __builtin_amdgcn_mfma_f32_16x16x32_bf16(a1, b1, c[1][1], 0, 0, 0);
        }
        __syncthreads();
    }
    #pragma unroll
    for (int i = 0; i < 2; ++i)
    #pragma unroll
    for (int j = 0; j < 2; ++j) {
        int m0 = row0 + wm * 32 + i * 16 + (lane >> 4) * 4;   // b index
        int nn = wn * 32 + j * 16 + (lane & 15);              // j within head
        #pragma unroll
        for (int r = 0; r < 4; ++r) {
            float v = c[i][j][r] + bv[h * 64 + nn];
            outh[(size_t)(m0 + r) * EMB + h * 64 + nn] = f2bf(v);
        }
    }
}

// out[:, 1024:2048] = cell
__global__ __launch_bounds__(256) void concat_kernel(
    const float* __restrict__ cell, float* __restrict__ out)
{
    const int b = blockIdx.x, t = threadIdx.x;
    *(f32x4*)&out[(size_t)b * 2048 + 1024 + t * 4] =
        *(const f32x4*)&cell[(size_t)b * 1024 + t * 4];
}

// ---------------------------------------------------------------------------
extern "C" void kernel_launch(void* const* d_in, const int* in_sizes, int n_in,
                              void* d_out, int out_size, void* d_ws, size_t ws_size,
                              hipStream_t stream)
{
    const float* x_nodes = (const float*)d_in[0];
    const float* cell    = (const float*)d_in[1];
    const float* Wq      = (const float*)d_in[2];
    const float* bq      = (const float*)d_in[3];
    const float* Wk      = (const float*)d_in[4];
    // d_in[5] = bk: softmax-invariant, dropped
    const float* Wv      = (const float*)d_in[6];
    const float* bv      = (const float*)d_in[7];
    const float* Wo      = (const float*)d_in[8];
    const float* bo      = (const float*)d_in[9];
    const float* Wc      = (const float*)d_in[10];
    const float* bc      = (const float*)d_in[11];
    const int*   guide   = (const int*)d_in[12];
    const int N = in_sizes[12];
    float* out = (float*)d_out;

    // workspace layout (19.0 MB peak — same footprint as the passing round-3 run).
    // qf32 (2 MB) is dead after qk_kernel; Wv_bf (0.5 MB) is converted into that
    // slot afterwards, so no new workspace is consumed.
    char* ws = (char*)d_ws;
    int*   starts  = (int*)ws;
    float* qf32    = (float*)(ws + 4096);                    // 2 MB (dead after qk)
    short* Wv_bf   = (short*)(ws + 4096);                    // 0.5 MB, overlaps qf32
    short* cell_bf = (short*)(ws + 4096 + (2u << 20));       // 1 MB
    short* cq_bf   = (short*)(ws + 4096 + (3u << 20));       // 1 MB
    short* outh_bf = (short*)(ws + 4096 + (4u << 20));       // 1 MB
    short* qk_bf   = (short*)(ws + 4096 + (5u << 20));       // 4 MB
    short* xbar_bf = (short*)(ws + 4096 + (9u << 20));       // 4 MB
    short* Wc_bf   = (short*)(ws + 4096 + (13u << 20));      // 2 MB
    short* Wq_bf   = (short*)(ws + 4096 + (15u << 20));      // 2 MB
    short* Wo_bf   = (short*)(ws + 4096 + (17u << 20));      // 2 MB

    starts_kernel<<<3, 256, 0, stream>>>(guide, N, starts);
    cvt_bf16<<<512, 256, 0, stream>>>(cell, cell_bf, (512 * 1024) / 4);
    cvt_bf16<<<512, 256, 0, stream>>>(Wc, Wc_bf, (1024 * 1024) / 4);
    cvt_bf16<<<512, 256, 0, stream>>>(Wq, Wq_bf, (1024 * 1024) / 4);
    cvt_bf16<<<512, 256, 0, stream>>>(Wo, Wo_bf, (1024 * 1024) / 4);

    // cq = cell @ Wc^T + bc           (bf16 out)
    gemm_bf16_nt<true ><<<dim3(16, 8), 256, 0, stream>>>(
        cell_bf, 1024, Wc_bf, 1024, bc, cq_bf, 1024, 1.0f);
    // q = (cq @ Wq^T + bq) * 0.125    (fp32 out)
    gemm_bf16_nt<false><<<dim3(16, 8), 256, 0, stream>>>(
        cq_bf, 1024, Wq_bf, 1024, bq, qf32, 1024, 0.125f);

    qk_kernel<<<dim3(B_GRAPHS / 8, NH), 256, 0, stream>>>(qf32, Wk, qk_bf);

    // qf32 now dead -> convert Wv into its slot
    cvt_bf16<<<256, 256, 0, stream>>>(Wv, (short*)Wv_bf, (1024 * 256) / 4);

    attn_kernel<<<B_GRAPHS, 256, 0, stream>>>(x_nodes, qk_bf, starts, xbar_bf, N);
    outh_gemm<<<dim3(8, NH), 256, 0, stream>>>(xbar_bf, Wv_bf, bv, outh_bf);

    // out[:, :1024] = outh @ Wo^T + bo  (fp32, ldc=2048 -> concat layout)
    gemm_bf16_nt<false><<<dim3(16, 8), 256, 0, stream>>>(
        outh_bf, 1024, Wo_bf, 1024, bo, out, 2048, 1.0f);
    concat_kernel<<<B_GRAPHS, 256, 0, stream>>>(cell, out);

    (void)in_sizes; (void)n_in; (void)out_size; (void)ws_size;
}